// Round 8
// baseline (436.443 us; speedup 1.0000x reference)
//
#include <hip/hip_runtime.h>
#include <math.h>

#define NPOINTS (1 << 21)
#define LVL 16
#define TSIZE (1 << 19)
#define TMASK (TSIZE - 1)
#define PRIME2 2654435761u

typedef float f32x2 __attribute__((ext_vector_type(2)));
typedef float f32x4 __attribute__((ext_vector_type(4)));

struct ResArr {
    int   n[LVL];
    float fn[LVL];
};

// Request-count cut: h = cx ^ (cy*PRIME) means for even cx0 (no wrap),
// h10 == h00^1 and h11 == h01^1 -> both x-corners live in one 16B-aligned
// entry pair. Load the aligned pair (dwordx4) per y-row; only odd/wrapped
// lanes (~51%) issue the extra 8B loads under exec mask. Line requests per
// point-level: 4 -> ~3 (-25%). Values bit-identical to reference.
__global__ __launch_bounds__(256, 6) void hashgrid2d_kernel(
    const f32x2* __restrict__ xy,
    const f32x2* __restrict__ tables,
    f32x4* __restrict__ out,
    ResArr res)
{
    __shared__ f32x4 lds[256 * 5];   // 4 data + 1 pad slot per thread = 20 KB

    int tid = threadIdx.x;
    int p   = blockIdx.x * 256 + tid;

    f32x2 pt = __builtin_nontemporal_load(&xy[p]);

    size_t base = (size_t)blockIdx.x * 2048;   // block's first out4 index

    #pragma unroll
    for (int b = 0; b < 2; ++b) {        // two batches of 8 levels
        #pragma unroll
        for (int q = 0; q < 4; ++q) {    // 2 levels -> one float4 to LDS
            float f[4];
            #pragma unroll
            for (int j = 0; j < 2; ++j) {
                int l = b * 8 + q * 2 + j;
                int   N  = res.n[l];
                float fN = res.fn[l];

                float sx = pt.x * fN;
                float sy = pt.y * fN;
                float fx = floorf(sx);
                float fy = floorf(sy);
                float wx = sx - fx;
                float wy = sy - fy;
                int ix = (int)fx;
                int iy = (int)fy;

                // (i0 + d) % N with 0 <= i0 <= N (fp rounding edge included)
                int cx0 = (ix     >= N) ? ix - N     : ix;
                int cx1 = (ix + 1 >= N) ? ix + 1 - N : ix + 1;
                int cy0 = (iy     >= N) ? iy - N     : iy;
                int cy1 = (iy + 1 >= N) ? iy + 1 - N : iy + 1;

                unsigned hy0 = (unsigned)cy0 * PRIME2;
                unsigned hy1 = (unsigned)cy1 * PRIME2;
                unsigned h00 = ((unsigned)cx0 ^ hy0) & TMASK;
                unsigned h10 = ((unsigned)cx1 ^ hy0) & TMASK;
                unsigned h01 = ((unsigned)cx0 ^ hy1) & TMASK;
                unsigned h11 = ((unsigned)cx1 ^ hy1) & TMASK;

                const f32x2* tbl = tables + (size_t)l * TSIZE;

                // Aligned entry-pairs containing h00 (and h00^1), h01 (h01^1).
                f32x4 P0 = *(const f32x4*)(tbl + (h00 & ~1u));
                f32x4 P1 = *(const f32x4*)(tbl + (h01 & ~1u));

                bool o0 = (h00 & 1u);
                bool o1 = (h01 & 1u);
                f32x2 c00 = o0 ? (f32x2){P0.z, P0.w} : (f32x2){P0.x, P0.y};
                f32x2 c10 = o0 ? (f32x2){P0.x, P0.y} : (f32x2){P0.z, P0.w};
                f32x2 c01 = o1 ? (f32x2){P1.z, P1.w} : (f32x2){P1.x, P1.y};
                f32x2 c11 = o1 ? (f32x2){P1.x, P1.y} : (f32x2){P1.z, P1.w};

                // Pair trick valid iff cx1 == cx0+1 with cx0 even; else
                // (odd cx0, or wrap at N-1) fetch the true x1 corners.
                if ((cx0 & 1) || (cx1 != cx0 + 1)) {
                    c10 = tbl[h10];
                    c11 = tbl[h11];
                }

                float omx = 1.0f - wx, omy = 1.0f - wy;
                float f0x = c00.x * omx + c10.x * wx;
                float f0y = c00.y * omx + c10.y * wx;
                float f1x = c01.x * omx + c11.x * wx;
                float f1y = c01.y * omx + c11.y * wx;
                f[j * 2 + 0] = f0x * omy + f1x * wy;
                f[j * 2 + 1] = f0y * omy + f1y * wy;
            }
            f32x4 v = { f[0], f[1], f[2], f[3] };
            lds[tid * 5 + q] = v;
        }

        __syncthreads();

        // Store this batch's 4 float4 per point, lane-coalesced full lines.
        #pragma unroll
        for (int i = 0; i < 4; ++i) {
            int e  = i * 256 + tid;            // 0..1023
            int pp = e >> 2;                   // point within block
            int q  = e & 3;
            f32x4 v = lds[pp * 5 + q];
            __builtin_nontemporal_store(v, &out[base + pp * 8 + b * 4 + q]);
        }

        __syncthreads();   // batch 1 rewrites the same LDS
    }
}

extern "C" void kernel_launch(void* const* d_in, const int* in_sizes, int n_in,
                              void* d_out, int out_size, void* d_ws, size_t ws_size,
                              hipStream_t stream) {
    const f32x2* xy     = (const f32x2*)d_in[0];
    const f32x2* tables = (const f32x2*)d_in[1];
    f32x4* out = (f32x4*)d_out;

    ResArr res;
    double b = pow(2048.0 / 16.0, 1.0 / 15.0);
    for (int l = 0; l < LVL; ++l) {
        int N = (int)llround(16.0 * pow(b, (double)l));
        res.n[l]  = N;
        res.fn[l] = (float)N;
    }

    dim3 block(256);
    dim3 grid(NPOINTS / 256);
    hashgrid2d_kernel<<<grid, block, 0, stream>>>(xy, tables, out, res);
}

// Round 9
// 391.999 us; speedup vs baseline: 1.1134x; 1.1134x over previous
//
#include <hip/hip_runtime.h>
#include <math.h>

#define NPOINTS (1 << 21)
#define LVL 16
#define TSIZE (1 << 19)
#define TMASK (TSIZE - 1)
#define PRIME2 2654435761u

typedef float f32x2 __attribute__((ext_vector_type(2)));
typedef float f32x4 __attribute__((ext_vector_type(4)));

struct ResArr {
    int   n[LVL];
    float fn[LVL];
};

__device__ __forceinline__ f32x2 level_feat(const f32x2* __restrict__ tables,
                                            int l, int N, float fN, f32x2 pt)
{
    float sx = pt.x * fN;
    float sy = pt.y * fN;
    float fx = floorf(sx);
    float fy = floorf(sy);
    float wx = sx - fx;
    float wy = sy - fy;
    int ix = (int)fx;
    int iy = (int)fy;

    // (i0 + d) % N with 0 <= i0 <= N (fp rounding edge included)
    int cx0 = (ix     >= N) ? ix - N     : ix;
    int cx1 = (ix + 1 >= N) ? ix + 1 - N : ix + 1;
    int cy0 = (iy     >= N) ? iy - N     : iy;
    int cy1 = (iy + 1 >= N) ? iy + 1 - N : iy + 1;

    unsigned hy0 = (unsigned)cy0 * PRIME2;
    unsigned hy1 = (unsigned)cy1 * PRIME2;

    const f32x2* tbl = tables + (size_t)l * TSIZE;
    f32x2 c00 = tbl[(int)(((unsigned)cx0 ^ hy0) & TMASK)];
    f32x2 c10 = tbl[(int)(((unsigned)cx1 ^ hy0) & TMASK)];
    f32x2 c01 = tbl[(int)(((unsigned)cx0 ^ hy1) & TMASK)];
    f32x2 c11 = tbl[(int)(((unsigned)cx1 ^ hy1) & TMASK)];

    float omx = 1.0f - wx, omy = 1.0f - wy;
    float f0x = c00.x * omx + c10.x * wx;
    float f0y = c00.y * omx + c10.y * wx;
    float f1x = c01.x * omx + c11.x * wx;
    float f1y = c01.y * omx + c11.y * wx;

    f32x2 r;
    r.x = f0x * omy + f1x * wy;
    r.y = f0y * omy + f1y * wy;
    return r;
}

// ---- Pass 1: level-phased gather. blockIdx.y = phase j handles levels
// {j, j+8}; per-phase table working set <= ~4.1 MB -> resident in each XCD L2
// while that phase's blocks run (x-major dispatch => phases are ~temporally
// disjoint). ws is level-major f32x2[l][p]; NT full-line coalesced stores so
// the output stream doesn't evict the phase's tables. Tables use REGULAR
// loads (we WANT them cached in L2).
__global__ __launch_bounds__(256) void pass1_kernel(
    const f32x2* __restrict__ xy,
    const f32x2* __restrict__ tables,
    f32x2* __restrict__ ws,
    ResArr res)
{
    int tid = threadIdx.x;
    int j   = blockIdx.y;                    // phase 0..7
    int p0  = blockIdx.x * 1024 + tid;

    int   Na = res.n[j],     Nb = res.n[j + 8];
    float fa = res.fn[j],    fb = res.fn[j + 8];

    #pragma unroll
    for (int i = 0; i < 4; ++i) {
        int p = p0 + i * 256;
        f32x2 pt = __builtin_nontemporal_load(&xy[p]);

        f32x2 ra = level_feat(tables, j,     Na, fa, pt);
        f32x2 rb = level_feat(tables, j + 8, Nb, fb, pt);

        __builtin_nontemporal_store(ra, &ws[(size_t)j       * NPOINTS + p]);
        __builtin_nontemporal_store(rb, &ws[(size_t)(j + 8) * NPOINTS + p]);
    }
}

// ---- Pass 2: transpose ws (level-major) -> out (point-major), pure stream.
// Reads: 16 coalesced 8B/lane segments. Writes: LDS-staged full-line NT
// stores (the proven 262 MB path from round 3).
__global__ __launch_bounds__(256) void pass2_kernel(
    const f32x2* __restrict__ ws,
    f32x4* __restrict__ out)
{
    __shared__ f32x4 lds[256 * 9];
    int tid = threadIdx.x;
    int p   = blockIdx.x * 256 + tid;

    #pragma unroll
    for (int c = 0; c < 8; ++c) {            // out4 chunk c = levels 2c, 2c+1
        f32x2 a = __builtin_nontemporal_load(&ws[(size_t)(2 * c)     * NPOINTS + p]);
        f32x2 b = __builtin_nontemporal_load(&ws[(size_t)(2 * c + 1) * NPOINTS + p]);
        f32x4 v = { a.x, a.y, b.x, b.y };
        lds[tid * 9 + c] = v;
    }
    __syncthreads();

    size_t base = (size_t)blockIdx.x * 2048;
    #pragma unroll
    for (int i = 0; i < 8; ++i) {
        int g = i * 256 + tid;
        f32x4 v = lds[(g >> 3) * 9 + (g & 7)];
        __builtin_nontemporal_store(v, &out[base + g]);
    }
}

// ---- Fallback (ws too small): round-7 single-pass kernel (433 us).
__global__ __launch_bounds__(256, 6) void hashgrid2d_fallback(
    const f32x2* __restrict__ xy,
    const f32x2* __restrict__ tables,
    f32x4* __restrict__ out,
    ResArr res)
{
    __shared__ f32x4 lds[256 * 5];

    int tid = threadIdx.x;
    int p   = blockIdx.x * 256 + tid;

    f32x2 pt = __builtin_nontemporal_load(&xy[p]);
    size_t base = (size_t)blockIdx.x * 2048;

    #pragma unroll
    for (int b = 0; b < 2; ++b) {
        #pragma unroll
        for (int q = 0; q < 4; ++q) {
            float f[4];
            #pragma unroll
            for (int j = 0; j < 2; ++j) {
                int l = b * 8 + q * 2 + j;
                f32x2 r = level_feat(tables, l, res.n[l], res.fn[l], pt);
                f[j * 2 + 0] = r.x;
                f[j * 2 + 1] = r.y;
            }
            f32x4 v = { f[0], f[1], f[2], f[3] };
            lds[tid * 5 + q] = v;
        }
        __syncthreads();
        #pragma unroll
        for (int i = 0; i < 4; ++i) {
            int e  = i * 256 + tid;
            int pp = e >> 2;
            int q  = e & 3;
            f32x4 v = lds[pp * 5 + q];
            __builtin_nontemporal_store(v, &out[base + pp * 8 + b * 4 + q]);
        }
        __syncthreads();
    }
}

extern "C" void kernel_launch(void* const* d_in, const int* in_sizes, int n_in,
                              void* d_out, int out_size, void* d_ws, size_t ws_size,
                              hipStream_t stream) {
    const f32x2* xy     = (const f32x2*)d_in[0];
    const f32x2* tables = (const f32x2*)d_in[1];
    f32x4* out = (f32x4*)d_out;

    ResArr res;
    double b = pow(2048.0 / 16.0, 1.0 / 15.0);
    for (int l = 0; l < LVL; ++l) {
        int N = (int)llround(16.0 * pow(b, (double)l));
        res.n[l]  = N;
        res.fn[l] = (float)N;
    }

    const size_t WS_NEED = (size_t)LVL * NPOINTS * sizeof(f32x2);  // 256 MiB

    if (ws_size >= WS_NEED) {
        f32x2* ws = (f32x2*)d_ws;
        dim3 g1(NPOINTS / 1024, 8);
        pass1_kernel<<<g1, 256, 0, stream>>>(xy, tables, ws, res);
        pass2_kernel<<<NPOINTS / 256, 256, 0, stream>>>(ws, out);
    } else {
        hashgrid2d_fallback<<<NPOINTS / 256, 256, 0, stream>>>(xy, tables, out, res);
    }
}